// Round 5
// baseline (28.646 us; speedup 1.0000x reference)
//
#include <hip/hip_runtime.h>

// TemporalCoding: out[b][t][f] = (spike_time(x[b][f]) == t && x[b][f] > 0) ? 1 : 0
// B=32, T=32, F=32768. Output 128 MiB f32 -> pure write-BW bound.
//
// R4 = R3 with the nontemporal store fixed: __builtin_nontemporal_store needs
// a native clang vector type, not HIP_vector_type<float,4>. Use
// ext_vector_type(4) float for the output stream.
// Layout: linear fill-clone write stream, wave-chunked ILP 8 (thread owns
// 128 B, block owns 32 KiB linear, 4096 blocks). Every store: 64 lanes x 16 B
// = 1 KiB contiguous.

constexpr int T   = 32;
constexpr int B   = 32;
constexpr int F   = 32768;
constexpr int NF4 = F / 4;        // 8192 float4 per (b,t) plane
constexpr int ILP = 8;            // float4 per thread, wave-chunked

typedef float f32x4 __attribute__((ext_vector_type(4)));

__global__ __launch_bounds__(256)
void temporal_coding_kernel(const f32x4* __restrict__ x4, f32x4* __restrict__ out4) {
    const unsigned bid = blockIdx.x;   // chunk id: b*128 + t*4 + c   (2048 f4 per chunk)
    const unsigned tid = threadIdx.x;

    const int      t    = (bid >> 2) & (T - 1);
    const f32x4*   xrow = x4 + ((size_t)(bid >> 7) << 13);          // + b*NF4
    // wave-chunked layout inside the 2048-float4 block chunk:
    // thread's k-th f4 at wave*512 + k*64 + lane
    const unsigned sub  = ((tid >> 6) << 9) | (tid & 63);
    const unsigned f4_0 = ((bid & 3) << 11) + sub;                  // f4 within plane
    f32x4*         op   = out4 + (((size_t)bid) << 11) + sub;       // linear stream

#pragma unroll
    for (int k = 0; k < ILP; ++k) {
        const f32x4 xv = xrow[f4_0 + k * 64];
        f32x4 r;
#pragma unroll
        for (int j = 0; j < 4; ++j) {
            float xn = xv[j];
            xn = xn < 0.0f ? 0.0f : (xn > 1.0f ? 1.0f : xn);
            int s = (int)((1.0f - xn) * 31.0f);   // trunc == astype(int32) for s>=0
            s = s < 0 ? 0 : (s > 31 ? 31 : s);
            r[j] = (xn > 0.0f && s == t) ? 1.0f : 0.0f;
        }
        __builtin_nontemporal_store(r, op + k * 64);
    }
}

extern "C" void kernel_launch(void* const* d_in, const int* in_sizes, int n_in,
                              void* d_out, int out_size, void* d_ws, size_t ws_size,
                              hipStream_t stream) {
    const f32x4* x4 = (const f32x4*)d_in[0];
    f32x4* out4 = (f32x4*)d_out;

    const int grid = B * T * NF4 / (256 * ILP);   // 4096 blocks, 256 threads, 8 f4/thread
    temporal_coding_kernel<<<grid, 256, 0, stream>>>(x4, out4);
}

// Round 6
// 25.295 us; speedup vs baseline: 1.1325x; 1.1325x over previous
//
#include <hip/hip_runtime.h>

// TemporalCoding: out[b][t][f] = (spike_time(x[b][f]) == t && x[b][f] > 0) ? 1 : 0
// B=32, T=32, F=32768. Output 128 MiB f32 -> pure write-BW bound.
//
// R5 = R4 minus nontemporal stores (isolation: R4 changed nt+ILP together and
// regressed 24.8 -> 28.6 us; hypothesis is nt hurt the streaming write path).
// Layout: linear fill-clone write stream, wave-chunked ILP 8 (thread owns
// 128 B, block owns 32 KiB linear, 4096 blocks). Every store: 64 lanes x 16 B
// = 1 KiB contiguous; plain global_store_dwordx4 (L2 write-buffered).

constexpr int T   = 32;
constexpr int B   = 32;
constexpr int F   = 32768;
constexpr int NF4 = F / 4;        // 8192 float4 per (b,t) plane
constexpr int ILP = 8;            // float4 per thread, wave-chunked

typedef float f32x4 __attribute__((ext_vector_type(4)));

__global__ __launch_bounds__(256)
void temporal_coding_kernel(const f32x4* __restrict__ x4, f32x4* __restrict__ out4) {
    const unsigned bid = blockIdx.x;   // chunk id: b*128 + t*4 + c   (2048 f4 per chunk)
    const unsigned tid = threadIdx.x;

    const int      t    = (bid >> 2) & (T - 1);
    const f32x4*   xrow = x4 + ((size_t)(bid >> 7) << 13);          // + b*NF4
    // wave-chunked layout inside the 2048-float4 block chunk:
    // thread's k-th f4 at wave*512 + k*64 + lane
    const unsigned sub  = ((tid >> 6) << 9) | (tid & 63);
    const unsigned f4_0 = ((bid & 3) << 11) + sub;                  // f4 within plane
    f32x4*         op   = out4 + (((size_t)bid) << 11) + sub;       // linear stream

#pragma unroll
    for (int k = 0; k < ILP; ++k) {
        const f32x4 xv = xrow[f4_0 + k * 64];
        f32x4 r;
#pragma unroll
        for (int j = 0; j < 4; ++j) {
            float xn = xv[j];
            xn = xn < 0.0f ? 0.0f : (xn > 1.0f ? 1.0f : xn);
            int s = (int)((1.0f - xn) * 31.0f);   // trunc == astype(int32) for s>=0
            s = s < 0 ? 0 : (s > 31 ? 31 : s);
            r[j] = (xn > 0.0f && s == t) ? 1.0f : 0.0f;
        }
        op[k * 64] = r;
    }
}

extern "C" void kernel_launch(void* const* d_in, const int* in_sizes, int n_in,
                              void* d_out, int out_size, void* d_ws, size_t ws_size,
                              hipStream_t stream) {
    const f32x4* x4 = (const f32x4*)d_in[0];
    f32x4* out4 = (f32x4*)d_out;

    const int grid = B * T * NF4 / (256 * ILP);   // 4096 blocks, 256 threads, 8 f4/thread
    temporal_coding_kernel<<<grid, 256, 0, stream>>>(x4, out4);
}

// Round 7
// 24.855 us; speedup vs baseline: 1.1525x; 1.0177x over previous
//
#include <hip/hip_runtime.h>

// TemporalCoding: out[b][t][f] = (spike_time(x[b][f]) == t && x[b][f] > 0) ? 1 : 0
// B=32, T=32, F=32768. Output 128 MiB f32 -> pure write-BW bound.
//
// R6: x-in-registers, full-t loop. 256 blocks x 256 threads; each block owns a
// 1024-float4 (16 KiB) f-chunk of one batch row. Load x ONCE into VGPRs,
// precompute spike times (inactive -> -1), then for t = 0..31 write a 16 KiB
// linear burst into plane t (plane stride 128 KiB). Eliminates the 128 MiB of
// L2 re-reads and 32x of the VMEM load issues that R2 paid for its linear
// stream. Stores remain 64 lanes x 16 B = 1 KiB contiguous per instruction,
// 4 KiB per wave per plane, 16 KiB per block per plane.

constexpr int T    = 32;
constexpr int B    = 32;
constexpr int F    = 32768;
constexpr int NF4  = F / 4;        // 8192 float4 per (b,t) plane
constexpr int RPT  = 4;            // float4 per thread, held in registers
constexpr int CHUNK = 256 * RPT;   // 1024 float4 per block

typedef float f32x4 __attribute__((ext_vector_type(4)));

__global__ __launch_bounds__(256)
void temporal_coding_kernel(const f32x4* __restrict__ x4, f32x4* __restrict__ out4) {
    const unsigned bid = blockIdx.x;          // b*8 + c  (8 chunks per batch row)
    const unsigned tid = threadIdx.x;

    const unsigned b = bid >> 3;
    const unsigned c = bid & 7;
    // wave-chunked: thread's k-th f4 at wave*256 + k*64 + lane within the chunk
    const unsigned sub = ((tid >> 6) << 8) | (tid & 63);

    const f32x4* xp = x4 + ((size_t)b << 13) + (c << 10) + sub;

    // load x once, compute spike times (st = -1 when inactive)
    int st[RPT][4];
#pragma unroll
    for (int k = 0; k < RPT; ++k) {
        const f32x4 xv = xp[k * 64];
#pragma unroll
        for (int j = 0; j < 4; ++j) {
            float xn = xv[j];
            xn = xn < 0.0f ? 0.0f : (xn > 1.0f ? 1.0f : xn);
            int s = (int)((1.0f - xn) * 31.0f);   // trunc == astype(int32), s in [0,31]
            s = s < 0 ? 0 : (s > 31 ? 31 : s);
            st[k][j] = (xn > 0.0f) ? s : -1;      // -1 never matches t
        }
    }

    // out4 + b*T*NF4 + c*1024 + sub; plane stride NF4
    f32x4* op = out4 + ((size_t)b << 18) + (c << 10) + sub;

#pragma unroll
    for (int t = 0; t < T; ++t) {
#pragma unroll
        for (int k = 0; k < RPT; ++k) {
            f32x4 r;
            r[0] = (st[k][0] == t) ? 1.0f : 0.0f;
            r[1] = (st[k][1] == t) ? 1.0f : 0.0f;
            r[2] = (st[k][2] == t) ? 1.0f : 0.0f;
            r[3] = (st[k][3] == t) ? 1.0f : 0.0f;
            op[(size_t)t * NF4 + k * 64] = r;
        }
    }
}

extern "C" void kernel_launch(void* const* d_in, const int* in_sizes, int n_in,
                              void* d_out, int out_size, void* d_ws, size_t ws_size,
                              hipStream_t stream) {
    const f32x4* x4 = (const f32x4*)d_in[0];
    f32x4* out4 = (f32x4*)d_out;

    const int grid = B * NF4 / CHUNK;   // 256 blocks, 256 threads, 4 f4/thread
    temporal_coding_kernel<<<grid, 256, 0, stream>>>(x4, out4);
}